// Round 5
// baseline (510.729 us; speedup 1.0000x reference)
//
#include <hip/hip_runtime.h>
#include <stdint.h>

// Batched Viterbi decode: B=8192, T=512, K=12.
// 16 lanes per batch row (12 tag-lanes + 4 pad), 4 rows per wave.
// Per-step exchange: lane j writes its trellis value (ds_write_b32); each
// lane reads ONE 16B chunk of the group's 12-float row (ds_read_b128); the
// ordered 12-vector is assembled with 12 quad_perm DPP broadcasts.
// Value chain: 12 adds -> v_max3 tree -> +emit. Argmax off-chain via exact
// first-index equality scan. Emissions pipelined one 8-step block ahead in
// named regs. Backpointers packed 4 steps/dword: bpw[b][w][j], w in [0,128).
//
// __launch_bounds__(256, 2): we launch exactly 2048 waves (2/SIMD), so give
// the register allocator the full 256-VGPR budget — at the default (64 VGPR)
// the scheduler sinks the emission prefetch loads to their uses, putting
// ~700 cyc of memory latency on the loop-carried chain every step (R4 wall
// was ~750 cyc/wave-step vs ~140 cyc of VALU issue).
//
// Output = [scores: B floats][paths: B*T floats].

namespace {

constexpr int kB = 8192;
constexpr int kT = 512;
constexpr int kK = 12;
constexpr int kW = 128;

template <int CTRL>
__device__ __forceinline__ float dppb(float x) {
    // quad_perm broadcast: CTRL=0x00 -> quad lane0, 0x55 -> lane1, 0xAA -> lane2
    return __int_as_float(__builtin_amdgcn_update_dpp(
        0, __float_as_int(x), CTRL, 0xf, 0xf, true));
}

__global__ __launch_bounds__(256, 2) void viterbi_fused(
    const float* __restrict__ logits,   // [B, T, K]
    const float* __restrict__ trans,    // [K, K]
    float* __restrict__ out,            // [B] scores + [B*T] paths
    uint32_t* __restrict__ bpw)         // [B, kW, kK]
{
    __shared__ __align__(64) float xch[16][16];   // 16 groups x 16 floats

    const int tid = blockIdx.x * 256 + threadIdx.x;
    const int b   = tid >> 4;
    const int j   = threadIdx.x & 15;
    const int g   = threadIdx.x >> 4;             // group within block
    const int jeff = (j < kK) ? j : (kK - 1);
    const int chunk = ((j & 3) == 3) ? 2 : (j & 3);

    float* __restrict__ xg = &xch[g][0];
    const float4* __restrict__ xgc = (const float4*)(xg + 4 * chunk);

    // transitions column jeff
    const float T0  = trans[0*kK+jeff],  T1  = trans[1*kK+jeff];
    const float T2  = trans[2*kK+jeff],  T3  = trans[3*kK+jeff];
    const float T4  = trans[4*kK+jeff],  T5  = trans[5*kK+jeff];
    const float T6  = trans[6*kK+jeff],  T7  = trans[7*kK+jeff];
    const float T8  = trans[8*kK+jeff],  T9  = trans[9*kK+jeff];
    const float T10 = trans[10*kK+jeff], T11 = trans[11*kK+jeff];

    const float* __restrict__ em = logits + (size_t)b * kT * kK + jeff;
    uint32_t* __restrict__ bpb = bpw + (size_t)b * kW * kK;

    float prev = em[0];

    // emissions for t = 1..8 in named regs
    float e0 = em[1*kK], e1 = em[2*kK], e2 = em[3*kK], e3 = em[4*kK];
    float e4 = em[5*kK], e5 = em[6*kK], e6 = em[7*kK], e7 = em[8*kK];

    uint32_t packed = 0;

#define EMLOAD(t) em[((t) < kT ? (t) : (kT - 1)) * kK]

#define EXCHANGE()                                                           \
    xg[j] = prev;                                                            \
    const float4 Q = *xgc;                                                   \
    const float p0 = dppb<0x00>(Q.x), p1 = dppb<0x00>(Q.y);                  \
    const float p2 = dppb<0x00>(Q.z), p3 = dppb<0x00>(Q.w);                  \
    const float p4 = dppb<0x55>(Q.x), p5 = dppb<0x55>(Q.y);                  \
    const float p6 = dppb<0x55>(Q.z), p7 = dppb<0x55>(Q.w);                  \
    const float p8 = dppb<0xAA>(Q.x), p9 = dppb<0xAA>(Q.y);                  \
    const float p10 = dppb<0xAA>(Q.z), p11 = dppb<0xAA>(Q.w)

#define STEP(K, WBASE, EMIT) do {                                            \
    EXCHANGE();                                                              \
    const float c0 = p0 + T0,   c1 = p1 + T1;                                \
    const float c2 = p2 + T2,   c3 = p3 + T3;                                \
    const float c4 = p4 + T4,   c5 = p5 + T5;                                \
    const float c6 = p6 + T6,   c7 = p7 + T7;                                \
    const float c8 = p8 + T8,   c9 = p9 + T9;                                \
    const float c10 = p10 + T10, c11 = p11 + T11;                            \
    const float m0 = fmaxf(fmaxf(c0, c1), c2);                               \
    const float m1 = fmaxf(fmaxf(c3, c4), c5);                               \
    const float m2 = fmaxf(fmaxf(c6, c7), c8);                               \
    const float m3 = fmaxf(fmaxf(c9, c10), c11);                             \
    const float best = fmaxf(fmaxf(m0, m1), fmaxf(m2, m3));                  \
    int bi = 11;                                                             \
    bi = (c10 == best) ? 10 : bi;  bi = (c9 == best) ? 9 : bi;               \
    bi = (c8  == best) ?  8 : bi;  bi = (c7 == best) ? 7 : bi;               \
    bi = (c6  == best) ?  6 : bi;  bi = (c5 == best) ? 5 : bi;               \
    bi = (c4  == best) ?  4 : bi;  bi = (c3 == best) ? 3 : bi;               \
    bi = (c2  == best) ?  2 : bi;  bi = (c1 == best) ? 1 : bi;               \
    bi = (c0  == best) ?  0 : bi;                                            \
    prev = best + (EMIT);                                                    \
    packed |= (uint32_t)bi << (8 * ((K) & 3));                               \
    if (((K) & 3) == 3) {                                                    \
        if (j < kK) bpb[(size_t)((WBASE) + ((K) >> 2)) * kK + j] = packed;   \
        packed = 0;                                                          \
    }                                                                        \
} while (0)

    // main: t = 1..504 in 63 guard-free blocks of 8
    for (int n = 0; n < 63; ++n) {
        const int tb = 8 * n + 1;
        const int w0 = 2 * n;
        // prefetch next block's emissions (t = tb+8 .. tb+15, clamped)
        const float f0 = EMLOAD(tb + 8),  f1 = EMLOAD(tb + 9);
        const float f2 = EMLOAD(tb + 10), f3 = EMLOAD(tb + 11);
        const float f4 = EMLOAD(tb + 12), f5 = EMLOAD(tb + 13);
        const float f6 = EMLOAD(tb + 14), f7 = EMLOAD(tb + 15);

        STEP(0, w0, e0); STEP(1, w0, e1); STEP(2, w0, e2); STEP(3, w0, e3);
        STEP(4, w0, e4); STEP(5, w0, e5); STEP(6, w0, e6); STEP(7, w0, e7);

        e0 = f0; e1 = f1; e2 = f2; e3 = f3;
        e4 = f4; e5 = f5; e6 = f6; e7 = f7;
    }

    // tail: t = 505..511 (e0..e6 hold em[505..511]); steps s = 504..510
    STEP(0, 126, e0); STEP(1, 126, e1); STEP(2, 126, e2); STEP(3, 126, e3);
    STEP(4, 126, e4); STEP(5, 126, e5); STEP(6, 126, e6);
    if (j < kK) bpb[(size_t)127 * kK + j] = packed;   // flush word 127 (3 bytes)

#undef STEP
#undef EMLOAD

    // final argmax over tags (first-index on ties)
    float best, v0, v1, v2, v3, v4, v5, v6, v7, v8, v9, v10, v11;
    {
        EXCHANGE();
        v0 = p0; v1 = p1; v2 = p2; v3 = p3; v4 = p4; v5 = p5;
        v6 = p6; v7 = p7; v8 = p8; v9 = p9; v10 = p10; v11 = p11;
        const float n0 = fmaxf(fmaxf(v0, v1), v2);
        const float n1 = fmaxf(fmaxf(v3, v4), v5);
        const float n2 = fmaxf(fmaxf(v6, v7), v8);
        const float n3 = fmaxf(fmaxf(v9, v10), v11);
        best = fmaxf(fmaxf(n0, n1), fmaxf(n2, n3));
    }
    int last = 11;
    last = (v10 == best) ? 10 : last;  last = (v9 == best) ? 9 : last;
    last = (v8  == best) ?  8 : last;  last = (v7 == best) ? 7 : last;
    last = (v6  == best) ?  6 : last;  last = (v5 == best) ? 5 : last;
    last = (v4  == best) ?  4 : last;  last = (v3 == best) ? 3 : last;
    last = (v2  == best) ?  2 : last;  last = (v1 == best) ? 1 : last;
    last = (v0  == best) ?  0 : last;

#undef EXCHANGE

    __syncthreads();  // drain backpointer stores before same-wave readback

    if (j == 0) {
        out[b] = best;
        float* __restrict__ paths = out + kB + (size_t)b * kT;
        paths[kT - 1] = (float)last;

        int tag = last;
        const uint4* __restrict__ r = (const uint4*)bpb;  // 3 uint4 per word
#pragma unroll 4
        for (int w = kW - 1; w >= 0; --w) {
            const uint4 q0 = r[w * 3 + 0];   // dwords j = 0..3
            const uint4 q1 = r[w * 3 + 1];   // j = 4..7
            const uint4 q2 = r[w * 3 + 2];   // j = 8..11
            const int smax = (w == kW - 1) ? 510 : (w * 4 + 3);
            for (int s = smax; s >= w * 4; --s) {
                const uint32_t ax = (tag & 8) ? q2.x : ((tag & 4) ? q1.x : q0.x);
                const uint32_t ay = (tag & 8) ? q2.y : ((tag & 4) ? q1.y : q0.y);
                const uint32_t az = (tag & 8) ? q2.z : ((tag & 4) ? q1.z : q0.z);
                const uint32_t aw = (tag & 8) ? q2.w : ((tag & 4) ? q1.w : q0.w);
                const uint32_t lo = (tag & 1) ? ay : ax;
                const uint32_t hi = (tag & 1) ? aw : az;
                const uint32_t dw = (tag & 2) ? hi : lo;
                tag = (int)((dw >> (8 * (s & 3))) & 0xFF);
                paths[s] = (float)tag;
            }
        }
    }
}

} // namespace

extern "C" void kernel_launch(void* const* d_in, const int* in_sizes, int n_in,
                              void* d_out, int out_size, void* d_ws, size_t ws_size,
                              hipStream_t stream) {
    const float* logits = (const float*)d_in[0];   // [8192, 512, 12] f32
    const float* trans  = (const float*)d_in[1];   // [12, 12] f32
    float* out = (float*)d_out;
    uint32_t* bpw = (uint32_t*)d_ws;               // 8192*128*12*4 = 50.3 MB

    const int threads = 256;
    const int blocks = (kB * 16) / threads;        // 512 blocks
    viterbi_fused<<<blocks, threads, 0, stream>>>(logits, trans, out, bpw);
}

// Round 6
// 510.414 us; speedup vs baseline: 1.0006x; 1.0006x over previous
//
#include <hip/hip_runtime.h>
#include <stdint.h>

// Batched Viterbi decode: B=8192, T=512, K=12.
// 16 lanes per batch row (12 tag-lanes + 4 pad), 4 rows per wave, 16 rows/block.
// Emissions staged via async global_load_lds DMA into double-buffered LDS
// chunks of 32 steps (each wave stages & reads only its own 4 rows -> no
// __syncthreads in the loop; completion enforced with explicit s_waitcnt).
// Per-step exchange: ds_write_b32 + ds_read_b128 + 12 quad_perm DPP broadcasts.
// Argmax off-chain via exact first-index equality scan. Backpointers packed
// 4 steps/dword: bpw[b][w][j], w in [0,128). Fused backtrack.
// Output = [scores: B floats][paths: B*T floats].

namespace {

constexpr int kB = 8192;
constexpr int kT = 512;
constexpr int kK = 12;
constexpr int kW = 128;
constexpr int kRowF = 392;   // LDS floats per row-chunk (384 used + 8 pad for banks)

template <int CTRL>
__device__ __forceinline__ float dppb(float x) {
    // quad_perm broadcast: CTRL=0x00 -> quad lane0, 0x55 -> lane1, 0xAA -> lane2
    return __int_as_float(__builtin_amdgcn_update_dpp(
        0, __float_as_int(x), CTRL, 0xf, 0xf, true));
}

__global__ __launch_bounds__(256, 2) void viterbi_fused(
    const float* __restrict__ logits,   // [B, T, K]
    const float* __restrict__ trans,    // [K, K]
    float* __restrict__ out,            // [B] scores + [B*T] paths
    uint32_t* __restrict__ bpw)         // [B, kW, kK]
{
    __shared__ __align__(64) float xch[16][16];           // 1 KB exchange rows
    __shared__ __align__(16) float embuf[2][16][kRowF];   // ~49 KB emission chunks

    const int j    = threadIdx.x & 15;
    const int g    = threadIdx.x >> 4;        // row within block 0..15
    const int wv   = threadIdx.x >> 6;        // wave 0..3
    const int ln   = threadIdx.x & 63;        // lane
    const int brow0 = blockIdx.x * 16;
    const int b    = brow0 + g;
    const int jeff = (j < kK) ? j : (kK - 1);
    const int xsel = ((j & 3) == 3) ? 2 : (j & 3);

    float* __restrict__ xg = &xch[g][0];
    const float4* __restrict__ xgc = (const float4*)(xg + 4 * xsel);

    // transitions column jeff
    const float T0  = trans[0*kK+jeff],  T1  = trans[1*kK+jeff];
    const float T2  = trans[2*kK+jeff],  T3  = trans[3*kK+jeff];
    const float T4  = trans[4*kK+jeff],  T5  = trans[5*kK+jeff];
    const float T6  = trans[6*kK+jeff],  T7  = trans[7*kK+jeff];
    const float T8  = trans[8*kK+jeff],  T9  = trans[9*kK+jeff];
    const float T10 = trans[10*kK+jeff], T11 = trans[11*kK+jeff];

    uint32_t* __restrict__ bpb = bpw + (size_t)b * kW * kK;

    // Async DMA of one 32-step chunk (384 floats/row) for this wave's 4 rows.
    // LDS dest is wave-uniform base + lane*4; global src = base + lane (floats).
#define DMA_CHUNK(c) do {                                                     \
    const int dsel_ = (c) & 1;                                                \
    const float* sbase_ = logits + (size_t)(brow0 + 4 * wv) * 6144            \
                          + (c) * 384 + ln;                                   \
    _Pragma("unroll")                                                         \
    for (int r4_ = 0; r4_ < 4; ++r4_) {                                       \
        _Pragma("unroll")                                                     \
        for (int p_ = 0; p_ < 6; ++p_) {                                      \
            const float* gsrc_ = sbase_ + r4_ * 6144 + p_ * 64;               \
            float* ldst_ = &embuf[dsel_][4 * wv + r4_][p_ * 64];              \
            __builtin_amdgcn_global_load_lds(                                 \
                (const __attribute__((address_space(1))) void*)gsrc_,         \
                (__attribute__((address_space(3))) void*)ldst_, 4, 0, 0);     \
        }                                                                     \
    }                                                                         \
} while (0)

    // emission read from staged LDS (t clamped into the resident range)
    auto emrd = [&](int t) -> float {
        const int tc = (t < kT) ? t : (kT - 1);
        return embuf[(tc >> 5) & 1][g][(tc & 31) * 12 + jeff];
    };

    DMA_CHUNK(0);
    DMA_CHUNK(1);

    float prev = logits[(size_t)b * 6144 + jeff];   // t = 0 emission (global)

    __builtin_amdgcn_wave_barrier();
    __builtin_amdgcn_s_waitcnt(0x0F70);   // vmcnt(0): chunks 0,1 landed
    __builtin_amdgcn_wave_barrier();

    float e0 = emrd(1), e1 = emrd(2), e2 = emrd(3), e3 = emrd(4);
    float e4 = emrd(5), e5 = emrd(6), e6 = emrd(7), e7 = emrd(8);

    uint32_t packed = 0;

#define EXCHANGE()                                                           \
    xg[j] = prev;                                                            \
    const float4 Q = *xgc;                                                   \
    const float p0 = dppb<0x00>(Q.x), p1 = dppb<0x00>(Q.y);                  \
    const float p2 = dppb<0x00>(Q.z), p3 = dppb<0x00>(Q.w);                  \
    const float p4 = dppb<0x55>(Q.x), p5 = dppb<0x55>(Q.y);                  \
    const float p6 = dppb<0x55>(Q.z), p7 = dppb<0x55>(Q.w);                  \
    const float p8 = dppb<0xAA>(Q.x), p9 = dppb<0xAA>(Q.y);                  \
    const float p10 = dppb<0xAA>(Q.z), p11 = dppb<0xAA>(Q.w)

#define STEP(K, WBASE, EMIT) do {                                            \
    EXCHANGE();                                                              \
    const float c0 = p0 + T0,   c1 = p1 + T1;                                \
    const float c2 = p2 + T2,   c3 = p3 + T3;                                \
    const float c4 = p4 + T4,   c5 = p5 + T5;                                \
    const float c6 = p6 + T6,   c7 = p7 + T7;                                \
    const float c8 = p8 + T8,   c9 = p9 + T9;                                \
    const float c10 = p10 + T10, c11 = p11 + T11;                            \
    const float m0 = fmaxf(fmaxf(c0, c1), c2);                               \
    const float m1 = fmaxf(fmaxf(c3, c4), c5);                               \
    const float m2 = fmaxf(fmaxf(c6, c7), c8);                               \
    const float m3 = fmaxf(fmaxf(c9, c10), c11);                             \
    const float best = fmaxf(fmaxf(m0, m1), fmaxf(m2, m3));                  \
    int bi = 11;                                                             \
    bi = (c10 == best) ? 10 : bi;  bi = (c9 == best) ? 9 : bi;               \
    bi = (c8  == best) ?  8 : bi;  bi = (c7 == best) ? 7 : bi;               \
    bi = (c6  == best) ?  6 : bi;  bi = (c5 == best) ? 5 : bi;               \
    bi = (c4  == best) ?  4 : bi;  bi = (c3 == best) ? 3 : bi;               \
    bi = (c2  == best) ?  2 : bi;  bi = (c1 == best) ? 1 : bi;               \
    bi = (c0  == best) ?  0 : bi;                                            \
    prev = best + (EMIT);                                                    \
    packed |= (uint32_t)bi << (8 * ((K) & 3));                               \
    if (((K) & 3) == 3) {                                                    \
        if (j < kK) bpb[(size_t)((WBASE) + ((K) >> 2)) * kK + j] = packed;   \
        packed = 0;                                                          \
    }                                                                        \
} while (0)

    // main: t = 1..504 in 63 sub-blocks of 8
    for (int n = 0; n < 63; ++n) {
        const int tb = 8 * n + 1;
        const int w0 = 2 * n;

        if ((n & 3) == 2) {
            // about to prefetch the first reads of a new chunk: ensure its DMA
            // (issued 3 sub-blocks ago, or in the preloop) has landed.
            __builtin_amdgcn_wave_barrier();
            __builtin_amdgcn_s_waitcnt(0x0F70);   // vmcnt(0)
            __builtin_amdgcn_wave_barrier();
        }
        if ((n & 3) == 3) {
            const int cc = (n >> 2) + 2;
            if (cc <= 15) {
                // overwrite buffer cc&1: all ds_reads of its old data issued in
                // earlier sub-blocks — drain LDS pipe before the DMA lands.
                __builtin_amdgcn_wave_barrier();
                __builtin_amdgcn_s_waitcnt(0xC07F);   // lgkmcnt(0)
                DMA_CHUNK(cc);
                __builtin_amdgcn_wave_barrier();
            }
        }

        // prefetch next sub-block's emissions from LDS
        const float f0 = emrd(tb + 8),  f1 = emrd(tb + 9);
        const float f2 = emrd(tb + 10), f3 = emrd(tb + 11);
        const float f4 = emrd(tb + 12), f5 = emrd(tb + 13);
        const float f6 = emrd(tb + 14), f7 = emrd(tb + 15);

        STEP(0, w0, e0); STEP(1, w0, e1); STEP(2, w0, e2); STEP(3, w0, e3);
        STEP(4, w0, e4); STEP(5, w0, e5); STEP(6, w0, e6); STEP(7, w0, e7);

        e0 = f0; e1 = f1; e2 = f2; e3 = f3;
        e4 = f4; e5 = f5; e6 = f6; e7 = f7;
    }

    // tail: t = 505..511 (e0..e6 hold em[505..511]); steps s = 504..510
    STEP(0, 126, e0); STEP(1, 126, e1); STEP(2, 126, e2); STEP(3, 126, e3);
    STEP(4, 126, e4); STEP(5, 126, e5); STEP(6, 126, e6);
    if (j < kK) bpb[(size_t)127 * kK + j] = packed;   // flush word 127 (3 bytes)

#undef STEP
#undef DMA_CHUNK

    // final argmax over tags (first-index on ties)
    float best, v0, v1, v2, v3, v4, v5, v6, v7, v8, v9, v10, v11;
    {
        EXCHANGE();
        v0 = p0; v1 = p1; v2 = p2; v3 = p3; v4 = p4; v5 = p5;
        v6 = p6; v7 = p7; v8 = p8; v9 = p9; v10 = p10; v11 = p11;
        const float n0 = fmaxf(fmaxf(v0, v1), v2);
        const float n1 = fmaxf(fmaxf(v3, v4), v5);
        const float n2 = fmaxf(fmaxf(v6, v7), v8);
        const float n3 = fmaxf(fmaxf(v9, v10), v11);
        best = fmaxf(fmaxf(n0, n1), fmaxf(n2, n3));
    }
    int last = 11;
    last = (v10 == best) ? 10 : last;  last = (v9 == best) ? 9 : last;
    last = (v8  == best) ?  8 : last;  last = (v7 == best) ? 7 : last;
    last = (v6  == best) ?  6 : last;  last = (v5 == best) ? 5 : last;
    last = (v4  == best) ?  4 : last;  last = (v3 == best) ? 3 : last;
    last = (v2  == best) ?  2 : last;  last = (v1 == best) ? 1 : last;
    last = (v0  == best) ?  0 : last;

#undef EXCHANGE

    __syncthreads();  // drain backpointer stores before same-wave readback

    if (j == 0) {
        out[b] = best;
        float* __restrict__ paths = out + kB + (size_t)b * kT;
        paths[kT - 1] = (float)last;

        int tag = last;
        const uint4* __restrict__ r = (const uint4*)bpb;  // 3 uint4 per word
#pragma unroll 4
        for (int w = kW - 1; w >= 0; --w) {
            const uint4 q0 = r[w * 3 + 0];   // dwords j = 0..3
            const uint4 q1 = r[w * 3 + 1];   // j = 4..7
            const uint4 q2 = r[w * 3 + 2];   // j = 8..11
            const int smax = (w == kW - 1) ? 510 : (w * 4 + 3);
            for (int s = smax; s >= w * 4; --s) {
                const uint32_t ax = (tag & 8) ? q2.x : ((tag & 4) ? q1.x : q0.x);
                const uint32_t ay = (tag & 8) ? q2.y : ((tag & 4) ? q1.y : q0.y);
                const uint32_t az = (tag & 8) ? q2.z : ((tag & 4) ? q1.z : q0.z);
                const uint32_t aw = (tag & 8) ? q2.w : ((tag & 4) ? q1.w : q0.w);
                const uint32_t lo = (tag & 1) ? ay : ax;
                const uint32_t hi = (tag & 1) ? aw : az;
                const uint32_t dw = (tag & 2) ? hi : lo;
                tag = (int)((dw >> (8 * (s & 3))) & 0xFF);
                paths[s] = (float)tag;
            }
        }
    }
}

} // namespace

extern "C" void kernel_launch(void* const* d_in, const int* in_sizes, int n_in,
                              void* d_out, int out_size, void* d_ws, size_t ws_size,
                              hipStream_t stream) {
    const float* logits = (const float*)d_in[0];   // [8192, 512, 12] f32
    const float* trans  = (const float*)d_in[1];   // [12, 12] f32
    float* out = (float*)d_out;
    uint32_t* bpw = (uint32_t*)d_ws;               // 8192*128*12*4 = 50.3 MB

    const int threads = 256;
    const int blocks = kB / 16;                    // 512 blocks
    viterbi_fused<<<blocks, threads, 0, stream>>>(logits, trans, out, bpw);
}

// Round 7
// 494.151 us; speedup vs baseline: 1.0335x; 1.0329x over previous
//
#include <hip/hip_runtime.h>
#include <stdint.h>

// Batched Viterbi decode: B=8192, T=512, K=12.
// 4 lanes per batch row (3 tag-columns per lane), 16 rows per 64-thread block.
// Exchange is 12 quad_perm DPP broadcasts — NO LDS on the loop-carried chain
// (R1-R6 all had an LDS round-trip + lgkmcnt waits per step => ~1500 cyc/step
// wall; this removes it). Emissions staged via async global_load_lds DMA into
// double-buffered 32-step LDS chunks (row stride 385 floats = conflict-free).
// Backpointers: 3 nibbles/lane/step packed in a ushort -> 8 B per (row,step).
// Fused backtrack, 16 rows SIMT-parallel. Output = [scores B][paths B*T floats].

namespace {

constexpr int kB = 8192;
constexpr int kT = 512;
constexpr int kK = 12;
constexpr int kRowF = 385;   // 384 staged floats + 1 pad (16 distinct bank shifts)

typedef float vf3 __attribute__((ext_vector_type(3)));

template <int CTRL>
__device__ __forceinline__ float dppb(float x) {
    // quad_perm broadcast of quad-lane q: CTRL = q * 0x55
    return __int_as_float(__builtin_amdgcn_update_dpp(
        0, __float_as_int(x), CTRL, 0xf, 0xf, true));
}

__global__ __launch_bounds__(64, 1) void viterbi_fused(
    const float* __restrict__ logits,   // [B, T, K]
    const float* __restrict__ trans,    // [K, K]
    float* __restrict__ out,            // [B] scores + [B*T] paths
    uint16_t* __restrict__ bp)          // [B][511][4] ushorts (3 nibbles each)
{
    __shared__ float embuf[2][16][kRowF];   // 49280 B

    const int ln    = threadIdx.x;      // 0..63
    const int row   = ln >> 2;          // 0..15
    const int c     = ln & 3;           // quad lane = column group
    const int brow0 = blockIdx.x * 16;
    const int b     = brow0 + row;
    const int j0    = 3 * c;            // this lane's columns j0..j0+2

    // transition columns j0, j0+1, j0+2 (36 regs)
    float TA[12], TB[12], TC[12];
#pragma unroll
    for (int i = 0; i < 12; ++i) {
        TA[i] = trans[i * kK + j0];
        TB[i] = trans[i * kK + j0 + 1];
        TC[i] = trans[i * kK + j0 + 2];
    }

    uint16_t* __restrict__ bps = bp + (size_t)b * 511 * 4 + c;

    // Async DMA of one 32-step chunk (384 floats/row) for all 16 rows.
    // LDS dest is wave-uniform base + lane*4; global src includes +ln.
#define DMA_CHUNK(cc) do {                                                    \
    const int dsel_ = (cc) & 1;                                               \
    _Pragma("unroll")                                                         \
    for (int r_ = 0; r_ < 16; ++r_) {                                         \
        const float* gs_ = logits + (size_t)(brow0 + r_) * (kT * kK)          \
                           + (cc) * 384 + ln;                                 \
        float* ld_ = &embuf[dsel_][r_][0];                                    \
        _Pragma("unroll")                                                     \
        for (int p_ = 0; p_ < 6; ++p_) {                                      \
            __builtin_amdgcn_global_load_lds(                                 \
                (const __attribute__((address_space(1))) void*)(gs_ + p_ * 64),\
                (__attribute__((address_space(3))) void*)(ld_ + p_ * 64),     \
                4, 0, 0);                                                     \
        }                                                                     \
    }                                                                         \
} while (0)

    // staged emission read: 3 consecutive floats for this lane's columns
    auto emrd = [&](int t) -> vf3 {
        const int tc = (t < kT) ? t : (kT - 1);
        return *(const vf3*)&embuf[(tc >> 5) & 1][row][(tc & 31) * 12 + j0];
    };

    DMA_CHUNK(0);
    DMA_CHUNK(1);

    __builtin_amdgcn_wave_barrier();
    __builtin_amdgcn_s_waitcnt(0x0F70);   // vmcnt(0): chunks 0,1 landed
    __builtin_amdgcn_wave_barrier();

    // trellis t=0 in n0..n2 (this lane's 3 columns)
    vf3 iv = emrd(0);
    float n0 = iv.x, n1 = iv.y, n2 = iv.z;

    vf3 e0 = emrd(1), e1 = emrd(2), e2 = emrd(3), e3 = emrd(4);
    vf3 e4 = emrd(5), e5 = emrd(6), e6 = emrd(7), e7 = emrd(8);

#define COLX(Tc, EMITc, NOUT, BIOUT) do {                                    \
    const float x0 = p0 + Tc[0],  x1 = p1 + Tc[1],  x2 = p2 + Tc[2];         \
    const float x3 = p3 + Tc[3],  x4 = p4 + Tc[4],  x5 = p5 + Tc[5];         \
    const float x6 = p6 + Tc[6],  x7 = p7 + Tc[7],  x8 = p8 + Tc[8];         \
    const float x9 = p9 + Tc[9],  x10 = p10 + Tc[10], x11 = p11 + Tc[11];    \
    const float mA = fmaxf(fmaxf(x0, x1), x2);                               \
    const float mB = fmaxf(fmaxf(x3, x4), x5);                               \
    const float mC = fmaxf(fmaxf(x6, x7), x8);                               \
    const float mD = fmaxf(fmaxf(x9, x10), x11);                             \
    const float best = fmaxf(fmaxf(mA, mB), fmaxf(mC, mD));                  \
    int bi = 11;                                                             \
    bi = (x10 == best) ? 10 : bi;  bi = (x9 == best) ? 9 : bi;               \
    bi = (x8  == best) ?  8 : bi;  bi = (x7 == best) ? 7 : bi;               \
    bi = (x6  == best) ?  6 : bi;  bi = (x5 == best) ? 5 : bi;               \
    bi = (x4  == best) ?  4 : bi;  bi = (x3 == best) ? 3 : bi;               \
    bi = (x2  == best) ?  2 : bi;  bi = (x1 == best) ? 1 : bi;               \
    bi = (x0  == best) ?  0 : bi;                                            \
    NOUT = best + (EMITc);  BIOUT = bi;                                      \
} while (0)

    // prev[3q+r] = quad-lane q's n_r
#define GATHER()                                                             \
    const float p0 = dppb<0x00>(n0), p1 = dppb<0x00>(n1), p2 = dppb<0x00>(n2);\
    const float p3 = dppb<0x55>(n0), p4 = dppb<0x55>(n1), p5 = dppb<0x55>(n2);\
    const float p6 = dppb<0xAA>(n0), p7 = dppb<0xAA>(n1), p8 = dppb<0xAA>(n2);\
    const float p9 = dppb<0xFF>(n0), p10 = dppb<0xFF>(n1), p11 = dppb<0xFF>(n2)

#define STEP(TT, EV) do {                                                    \
    GATHER();                                                                \
    float q0_, q1_, q2_; int b0_, b1_, b2_;                                  \
    COLX(TA, (EV).x, q0_, b0_);                                              \
    COLX(TB, (EV).y, q1_, b1_);                                              \
    COLX(TC, (EV).z, q2_, b2_);                                              \
    n0 = q0_; n1 = q1_; n2 = q2_;                                            \
    const uint32_t w_ = (uint32_t)b0_ | ((uint32_t)b1_ << 4)                 \
                        | ((uint32_t)b2_ << 8);                              \
    bps[(size_t)((TT) - 1) * 4] = (uint16_t)w_;                              \
} while (0)

    // main: t = 1..504 in 63 sub-blocks of 8
    for (int n = 0; n < 63; ++n) {
        const int tb = 8 * n + 1;

        if ((n & 3) == 2) {
            // next chunk's DMA (issued 3 sub-blocks ago) must have landed
            __builtin_amdgcn_wave_barrier();
            __builtin_amdgcn_s_waitcnt(0x0F70);   // vmcnt(0)
            __builtin_amdgcn_wave_barrier();
        }
        if ((n & 3) == 3) {
            const int cc = (n >> 2) + 2;
            if (cc <= 15) {
                // drain ds_reads of the buffer being overwritten
                __builtin_amdgcn_wave_barrier();
                __builtin_amdgcn_s_waitcnt(0xC07F);   // lgkmcnt(0)
                DMA_CHUNK(cc);
                __builtin_amdgcn_wave_barrier();
            }
        }

        const vf3 f0 = emrd(tb + 8),  f1 = emrd(tb + 9);
        const vf3 f2 = emrd(tb + 10), f3 = emrd(tb + 11);
        const vf3 f4 = emrd(tb + 12), f5 = emrd(tb + 13);
        const vf3 f6 = emrd(tb + 14), f7 = emrd(tb + 15);

        STEP(tb + 0, e0); STEP(tb + 1, e1); STEP(tb + 2, e2); STEP(tb + 3, e3);
        STEP(tb + 4, e4); STEP(tb + 5, e5); STEP(tb + 6, e6); STEP(tb + 7, e7);

        e0 = f0; e1 = f1; e2 = f2; e3 = f3;
        e4 = f4; e5 = f5; e6 = f6; e7 = f7;
    }

    // tail: t = 505..511 (e0..e6 hold em[505..511])
    STEP(505, e0); STEP(506, e1); STEP(507, e2); STEP(508, e3);
    STEP(509, e4); STEP(510, e5); STEP(511, e6);

#undef STEP
#undef DMA_CHUNK

    // final 12-way max + first-index argmax
    float best;
    int last;
    {
        GATHER();
        const float mA = fmaxf(fmaxf(p0, p1), p2);
        const float mB = fmaxf(fmaxf(p3, p4), p5);
        const float mC = fmaxf(fmaxf(p6, p7), p8);
        const float mD = fmaxf(fmaxf(p9, p10), p11);
        best = fmaxf(fmaxf(mA, mB), fmaxf(mC, mD));
        int bi = 11;
        bi = (p10 == best) ? 10 : bi;  bi = (p9 == best) ? 9 : bi;
        bi = (p8  == best) ?  8 : bi;  bi = (p7 == best) ? 7 : bi;
        bi = (p6  == best) ?  6 : bi;  bi = (p5 == best) ? 5 : bi;
        bi = (p4  == best) ?  4 : bi;  bi = (p3 == best) ? 3 : bi;
        bi = (p2  == best) ?  2 : bi;  bi = (p1 == best) ? 1 : bi;
        bi = (p0  == best) ?  0 : bi;
        last = bi;
    }
#undef GATHER
#undef COLX

    __syncthreads();   // drain backpointer stores before same-wave readback

    if (c == 0) {
        out[b] = best;
        float* __restrict__ paths = out + kB + (size_t)b * kT;
        paths[kT - 1] = (float)last;

        int tag = last;
        const uint2* __restrict__ rec = (const uint2*)(bp + (size_t)b * 511 * 4);
#pragma unroll 4
        for (int s = 510; s >= 0; --s) {
            const uint2 q = rec[s];
            const int d3 = (tag * 11) >> 5;        // tag / 3  (exact for 0..15)
            const int rm = tag - 3 * d3;           // tag % 3
            const uint32_t dw = (d3 & 2) ? q.y : q.x;
            const int sh = ((d3 & 1) << 4) + (rm << 2);
            tag = (int)((dw >> sh) & 0xF);
            paths[s] = (float)tag;
        }
    }
}

} // namespace

extern "C" void kernel_launch(void* const* d_in, const int* in_sizes, int n_in,
                              void* d_out, int out_size, void* d_ws, size_t ws_size,
                              hipStream_t stream) {
    const float* logits = (const float*)d_in[0];   // [8192, 512, 12] f32
    const float* trans  = (const float*)d_in[1];   // [12, 12] f32
    float* out = (float*)d_out;
    uint16_t* bp = (uint16_t*)d_ws;                // 8192*511*4*2 = 33.5 MB

    const int threads = 64;                        // 1 wave per block, 16 rows
    const int blocks = kB / 16;                    // 512 blocks
    viterbi_fused<<<blocks, threads, 0, stream>>>(logits, trans, out, bp);
}